// Round 5
// baseline (2991.211 us; speedup 1.0000x reference)
//
#include <hip/hip_runtime.h>

// ---- problem dims ----
#define NB 4096    // total peds (B)
#define HD 128     // H
#define ED 64      // E
#define NF 128     // frames
#define NP 32      // peds/frame
#define TSTEPS 12

typedef __attribute__((ext_vector_type(8))) short short8;
typedef __attribute__((ext_vector_type(8))) __bf16 bf16x8;
typedef __attribute__((ext_vector_type(8))) _Float16 f16x8;
typedef __attribute__((ext_vector_type(4))) float f32x4;

#define MFMA16(a, b, c) __builtin_amdgcn_mfma_f32_16x16x32_bf16((a), (b), (c), 0, 0, 0)
#define MFMAH(a, b, c)  __builtin_amdgcn_mfma_f32_16x16x32_f16((a), (b), (c), 0, 0, 0)

__device__ __forceinline__ unsigned short f2bf(float f) {
  unsigned int x = __float_as_uint(f);
  x += 0x7fffu + ((x >> 16) & 1u);
  return (unsigned short)(x >> 16);
}

__device__ __forceinline__ float sigm(float x) { return 1.0f / (1.0f + expf(-x)); }

__device__ __forceinline__ f16x8 relu8(f16x8 x) {
  return __builtin_elementwise_max(x, (f16x8)(_Float16)0);
}

// ---------------- pre-pass packs ----------------

__global__ __launch_bounds__(256) void k_transpose_bf(const float* __restrict__ W,
                                                      unsigned short* __restrict__ Wt,
                                                      int K, int N) {
  __shared__ float t[32][33];
  int nb = blockIdx.x * 32, kb = blockIdx.y * 32;
  int tx = threadIdx.x & 31, ty = threadIdx.x >> 5;
  #pragma unroll
  for (int r = 0; r < 32; r += 8)
    t[ty + r][tx] = W[(size_t)(kb + ty + r) * N + nb + tx];
  __syncthreads();
  #pragma unroll
  for (int r = 0; r < 32; r += 8)
    Wt[(size_t)(nb + ty + r) * K + kb + tx] = f2bf(t[tx][ty + r]);
}

__global__ __launch_bounds__(256) void k_transpose_f16(const float* __restrict__ W,
                                                       _Float16* __restrict__ Wt,
                                                       int K, int N) {
  __shared__ float t[32][33];
  int nb = blockIdx.x * 32, kb = blockIdx.y * 32;
  int tx = threadIdx.x & 31, ty = threadIdx.x >> 5;
  #pragma unroll
  for (int r = 0; r < 32; r += 8)
    t[ty + r][tx] = W[(size_t)(kb + ty + r) * N + nb + tx];
  __syncthreads();
  #pragma unroll
  for (int r = 0; r < 32; r += 8)
    Wt[(size_t)(nb + ty + r) * K + kb + tx] = (_Float16)t[tx][ty + r];
}

__global__ __launch_bounds__(256) void k_pack_lstm_w(const float* __restrict__ Wih,
                                                     const float* __restrict__ Whh,
                                                     float* __restrict__ WihT,
                                                     float* __restrict__ WhhT) {
  int idx = blockIdx.x * 256 + threadIdx.x;
  if (idx < 64 * 512) { int k = idx >> 9, n = idx & 511; WihT[idx] = Wih[n * 64 + k]; }
  if (idx < 128 * 512) { int k = idx >> 9, n = idx & 511; WhhT[idx] = Whh[n * 128 + k]; }
}

__global__ __launch_bounds__(256) void k_pack_wpp(const float* __restrict__ Wpe,
                                                  const float* __restrict__ bpe,
                                                  const float* __restrict__ Wp1,
                                                  const float* __restrict__ bp1,
                                                  float* __restrict__ Wpp,
                                                  float* __restrict__ cvec) {
  int n = blockIdx.x * 256 + threadIdx.x;
  if (n >= 512) return;
  float s0 = 0.f, s1 = 0.f, sc = 0.f;
  for (int k = 0; k < 64; ++k) {
    float w = Wp1[k * 512 + n];
    s0 += Wpe[k] * w;
    s1 += Wpe[64 + k] * w;
    sc += bpe[k] * w;
  }
  Wpp[n * 2] = s0; Wpp[n * 2 + 1] = s1; cvec[n] = sc + bp1[n];
}

__global__ __launch_bounds__(256) void k_x0(const float* __restrict__ ofr,
                                            const float* __restrict__ Wemb,
                                            const float* __restrict__ bemb,
                                            float* __restrict__ x) {
  int idx = blockIdx.x * 256 + threadIdx.x;
  if (idx >= NB * ED) return;
  int row = idx >> 6, e = idx & 63;
  x[idx] = bemb[e] + ofr[row * 2] * Wemb[e] + ofr[row * 2 + 1] * Wemb[64 + e];
}

// ---------------- per-step kernels ----------------

// K12: fused LSTM cell + pos + x_new + u/v build. 8 rows/block, 256 thr.
__global__ __launch_bounds__(256) void k12_lstm_uv(
    const float* __restrict__ x, const float* __restrict__ hin, const float* __restrict__ cin,
    const float* __restrict__ WihT, const float* __restrict__ WhhT,
    const float* __restrict__ bih, const float* __restrict__ bhh,
    const float* __restrict__ Wpos, const float* __restrict__ bpos,
    const float* __restrict__ Wemb, const float* __restrict__ bemb,
    const float* __restrict__ lastpos,
    const float* __restrict__ Wp1, const float* __restrict__ Wpp,
    const float* __restrict__ cvec,
    float* __restrict__ cout, unsigned short* __restrict__ mi,
    float* __restrict__ posout, float* __restrict__ xout,
    float* __restrict__ outc, float* __restrict__ outr,
    _Float16* __restrict__ u16, _Float16* __restrict__ v16) {
  __shared__ float xh[8][192];
  __shared__ float hnl[8][128];
  __shared__ float rp[8][2];
  __shared__ float cp[8][2];
  int tid = threadIdx.x;
  int r0 = blockIdx.x * 8;
  for (int idx = tid; idx < 8 * 192; idx += 256) {
    int r = idx / 192, k = idx % 192;
    xh[r][k] = (k < 64) ? x[(r0 + r) * 64 + k] : hin[(r0 + r) * 128 + (k - 64)];
  }
  __syncthreads();
  int j = tid & 127, rg = tid >> 7;
  float acc0[4], acc1[4], acc2[4], acc3[4];
  {
    float b0 = bih[j] + bhh[j];
    float b1 = bih[128 + j] + bhh[128 + j];
    float b2 = bih[256 + j] + bhh[256 + j];
    float b3 = bih[384 + j] + bhh[384 + j];
    #pragma unroll
    for (int r = 0; r < 4; ++r) { acc0[r] = b0; acc1[r] = b1; acc2[r] = b2; acc3[r] = b3; }
  }
  for (int k = 0; k < 64; ++k) {
    float w0 = WihT[k * 512 + j], w1 = WihT[k * 512 + 128 + j],
          w2 = WihT[k * 512 + 256 + j], w3 = WihT[k * 512 + 384 + j];
    #pragma unroll
    for (int r = 0; r < 4; ++r) {
      float xv = xh[rg * 4 + r][k];
      acc0[r] += w0 * xv; acc1[r] += w1 * xv; acc2[r] += w2 * xv; acc3[r] += w3 * xv;
    }
  }
  for (int k = 0; k < 128; ++k) {
    float w0 = WhhT[k * 512 + j], w1 = WhhT[k * 512 + 128 + j],
          w2 = WhhT[k * 512 + 256 + j], w3 = WhhT[k * 512 + 384 + j];
    #pragma unroll
    for (int r = 0; r < 4; ++r) {
      float hv = xh[rg * 4 + r][64 + k];
      acc0[r] += w0 * hv; acc1[r] += w1 * hv; acc2[r] += w2 * hv; acc3[r] += w3 * hv;
    }
  }
  #pragma unroll
  for (int r = 0; r < 4; ++r) {
    int row = r0 + rg * 4 + r;
    float ig = sigm(acc0[r]), fg = sigm(acc1[r]), gg = tanhf(acc2[r]), og = sigm(acc3[r]);
    float cn = fg * cin[row * 128 + j] + ig * gg;
    float hv = og * tanhf(cn);
    cout[row * 128 + j] = cn;
    mi[(size_t)row * 1152 + j] = f2bf(hv);
    hnl[rg * 4 + r][j] = hv;
  }
  __syncthreads();
  // parallel W_pos dot: 16 lanes per (row, dim)
  {
    int r = tid >> 5;
    int d = (tid >> 4) & 1;
    int l = tid & 15;
    float s = 0.f;
    #pragma unroll
    for (int k = l; k < 128; k += 16) s += hnl[r][k] * Wpos[k * 2 + d];
    s += __shfl_xor(s, 1);
    s += __shfl_xor(s, 2);
    s += __shfl_xor(s, 4);
    s += __shfl_xor(s, 8);
    if (l == 0) {
      int row = r0 + r;
      float rel = s + bpos[d];
      float cur = rel + lastpos[row * 2 + d];
      rp[r][d] = rel;
      cp[r][d] = cur;
      posout[row * 2 + d] = cur;
      outc[row * 2 + d] = cur;
      outr[row * 2 + d] = rel;
    }
  }
  __syncthreads();
  for (int idx = tid; idx < 8 * 64; idx += 256) {
    int r = idx >> 6, e = idx & 63;
    xout[(r0 + r) * 64 + e] = bemb[e] + rp[r][0] * Wemb[e] + rp[r][1] * Wemb[64 + e];
  }
  // ---- k2 part: u/v build (f16 out) ----
  int n = tid, n2 = tid + 256;
  float aA[8], aB[8];
  #pragma unroll
  for (int r = 0; r < 8; ++r) { aA[r] = 0.f; aB[r] = 0.f; }
  for (int k = 0; k < 128; ++k) {
    float wA = Wp1[(64 + k) * 512 + n], wB = Wp1[(64 + k) * 512 + n2];
    #pragma unroll
    for (int r = 0; r < 8; ++r) { aA[r] += wA * hnl[r][k]; aB[r] += wB * hnl[r][k]; }
  }
  float wp0A = Wpp[n * 2], wp1A = Wpp[n * 2 + 1], cA = cvec[n];
  float wp0B = Wpp[n2 * 2], wp1B = Wpp[n2 * 2 + 1], cB = cvec[n2];
  #pragma unroll
  for (int r = 0; r < 8; ++r) {
    int row = r0 + r;
    float t0 = cp[r][0] * wp0A + cp[r][1] * wp1A;
    v16[(size_t)row * 512 + n] = (_Float16)t0;
    u16[(size_t)row * 512 + n] = (_Float16)(t0 + aA[r] + cA);
    float t1 = cp[r][0] * wp0B + cp[r][1] * wp1B;
    v16[(size_t)row * 512 + n2] = (_Float16)t1;
    u16[(size_t)row * 512 + n2] = (_Float16)(t1 + aB[r] + cB);
  }
}

// K3 v5: pool_h[f,i,n] = relu(max_j ( relu(u_j - v_i) @ Wp2 )[n] + bp2[n])
// grid (128 f, 8 ig, 4 ng); 256 thr = 4 waves = 2 ip x 2 nh.
// wave = 2 i x 32 j x 128 cols: per K-32 step reads 2u + 2v + 8B b128, 32 MFMAs.
// Row stride 40 f16 (80 B) for B/u chunks: 20-dword row stride -> conflict-free
// ds_read_b128 pattern (R2-measured 0 conflicts). Single barrier per step,
// reg-prefetch of next chunk.
#define BSTR 40  // B LDS row stride (f16)
#define USTR 40  // u LDS row stride (f16)
__global__ __launch_bounds__(256, 2) void k3_pool(
    const _Float16* __restrict__ u16, const _Float16* __restrict__ v16,
    const _Float16* __restrict__ Bt, const float* __restrict__ bp2,
    unsigned short* __restrict__ mi) {
  __shared__ _Float16 v_lds[4 * 512];         //  4 KB
  __shared__ _Float16 u_ch[2][32 * USTR];     //  5 KB
  __shared__ _Float16 b_ch[2][256 * BSTR];    // 40 KB
  int f = blockIdx.x, ig = blockIdx.y, ng = blockIdx.z;
  int tid = threadIdx.x, wid = tid >> 6, lane = tid & 63;
  int c = lane & 15, q = lane >> 4;
  int ip = wid >> 1, nh = wid & 1;

  // staging maps: B 4 units/thr (rows tid>>2 + 64t, seg tid&3); u 1 unit for tid<128
  int srow = tid >> 2, sseg = tid & 3;
  const _Float16* gB = Bt + (size_t)(ng * 256 + srow) * 512 + sseg * 8;
  const _Float16* gU = u16 + (size_t)(f * 32 + srow) * 512 + sseg * 8;
  int lOff = srow * BSTR + sseg * 8;

  // v prologue: 4 rows x 512
  {
    int vr = tid >> 6, vs = tid & 63;
    *(f16x8*)(v_lds + vr * 512 + vs * 8) =
        *(const f16x8*)(v16 + (size_t)(f * 32 + ig * 4 + vr) * 512 + vs * 8);
  }
  // chunk 0
  #pragma unroll
  for (int t = 0; t < 4; ++t)
    *(f16x8*)(b_ch[0] + lOff + t * 64 * BSTR) = *(const f16x8*)(gB + (size_t)t * 64 * 512);
  if (tid < 128) *(f16x8*)(u_ch[0] + lOff) = *(const f16x8*)(gU);
  __syncthreads();

  f32x4 acc[2][2][8];  // [ii][jg][nt]
  #pragma unroll
  for (int a = 0; a < 2; ++a)
    #pragma unroll
    for (int b = 0; b < 2; ++b)
      #pragma unroll
      for (int n = 0; n < 8; ++n) acc[a][b][n] = (f32x4){0.f, 0.f, 0.f, 0.f};

  const _Float16* vb0 = v_lds + (ip * 2 + 0) * 512 + q * 8;
  const _Float16* vb1 = v_lds + (ip * 2 + 1) * 512 + q * 8;
  int uoff0 = c * USTR + q * 8;
  int uoff1 = (16 + c) * USTR + q * 8;
  int boff = (nh * 128 + c) * BSTR + q * 8;

  #pragma unroll 2
  for (int ks = 0; ks < 16; ++ks) {
    int cur = ks & 1;
    f16x8 rB0, rB1, rB2, rB3, rU;
    if (ks < 15) {
      const _Float16* g = gB + (size_t)(ks + 1) * 32;
      rB0 = *(const f16x8*)(g);
      rB1 = *(const f16x8*)(g + (size_t)64 * 512);
      rB2 = *(const f16x8*)(g + (size_t)128 * 512);
      rB3 = *(const f16x8*)(g + (size_t)192 * 512);
      if (tid < 128) rU = *(const f16x8*)(gU + (size_t)(ks + 1) * 32);
    }
    const _Float16* ub = u_ch[cur];
    const _Float16* bb = b_ch[cur];
    f16x8 uf0 = *(const f16x8*)(ub + uoff0);
    f16x8 uf1 = *(const f16x8*)(ub + uoff1);
    f16x8 vv0 = *(const f16x8*)(vb0 + ks * 32);
    f16x8 vv1 = *(const f16x8*)(vb1 + ks * 32);
    f16x8 a00 = relu8(uf0 - vv0), a01 = relu8(uf1 - vv0);
    f16x8 a10 = relu8(uf0 - vv1), a11 = relu8(uf1 - vv1);
    __builtin_amdgcn_s_setprio(1);
    #pragma unroll
    for (int nt = 0; nt < 8; ++nt) {
      f16x8 bf = *(const f16x8*)(bb + boff + nt * 16 * BSTR);
      acc[0][0][nt] = MFMAH(a00, bf, acc[0][0][nt]);
      acc[0][1][nt] = MFMAH(a01, bf, acc[0][1][nt]);
      acc[1][0][nt] = MFMAH(a10, bf, acc[1][0][nt]);
      acc[1][1][nt] = MFMAH(a11, bf, acc[1][1][nt]);
    }
    __builtin_amdgcn_s_setprio(0);
    if (ks < 15) {
      _Float16* lb = b_ch[cur ^ 1] + lOff;
      *(f16x8*)(lb) = rB0;
      *(f16x8*)(lb + 64 * BSTR) = rB1;
      *(f16x8*)(lb + 128 * BSTR) = rB2;
      *(f16x8*)(lb + 192 * BSTR) = rB3;
      if (tid < 128) *(f16x8*)(u_ch[cur ^ 1] + lOff) = rU;
    }
    __syncthreads();
  }

  // epilogue: max over j (4 regs x 2 jg + shfl over q), relu(+bias), write bf16
  int colbase = ng * 256 + nh * 128;
  #pragma unroll
  for (int ii = 0; ii < 2; ++ii) {
    int rowg = f * 32 + ig * 4 + ip * 2 + ii;
    #pragma unroll
    for (int nt = 0; nt < 8; ++nt) {
      f32x4 x0 = acc[ii][0][nt], x1 = acc[ii][1][nt];
      float m = fmaxf(fmaxf(fmaxf(x0[0], x0[1]), fmaxf(x0[2], x0[3])),
                      fmaxf(fmaxf(x1[0], x1[1]), fmaxf(x1[2], x1[3])));
      m = fmaxf(m, __shfl_xor(m, 16));
      m = fmaxf(m, __shfl_xor(m, 32));
      if (q == 0) {
        int col = colbase + nt * 16 + c;
        float val = fmaxf(m + bp2[col], 0.f);
        mi[(size_t)rowg * 1152 + 128 + col] = f2bf(val);
      }
    }
  }
}

// K4: nh1 = relu(mi @ W_m1 + b_m1), M=4096 K=1152 N=1024 (bf16 MFMA)
__global__ __launch_bounds__(512) void k4_mlp1(
    const unsigned short* __restrict__ mi, const unsigned short* __restrict__ Wt,
    const float* __restrict__ bm1, unsigned short* __restrict__ nh1) {
  int bid = blockIdx.x;
  int mb = bid & 63, nb = bid >> 6;
  int tid = threadIdx.x, wid = tid >> 6, lane = tid & 63;
  int row0 = mb * 64 + (wid >> 2) * 32;
  int nc0 = nb * 256 + (wid & 3) * 64;
  int c = lane & 15, q = lane >> 4;
  const unsigned short* a0p = mi + (size_t)(row0 + c) * 1152;
  const unsigned short* a1p = a0p + 16 * 1152;
  const unsigned short* bb = Wt + (size_t)(nc0 + c) * 1152;
  f32x4 acc[2][4];
  #pragma unroll
  for (int a = 0; a < 2; ++a)
    #pragma unroll
    for (int b = 0; b < 4; ++b) acc[a][b] = (f32x4){0.f, 0.f, 0.f, 0.f};
  for (int ks = 0; ks < 36; ++ks) {
    int k0 = ks * 32 + q * 8;
    bf16x8 a0 = *(const bf16x8*)(a0p + k0);
    bf16x8 a1 = *(const bf16x8*)(a1p + k0);
    #pragma unroll
    for (int nt = 0; nt < 4; ++nt) {
      bf16x8 bf = *(const bf16x8*)(bb + (size_t)nt * 16 * 1152 + k0);
      acc[0][nt] = MFMA16(a0, bf, acc[0][nt]);
      acc[1][nt] = MFMA16(a1, bf, acc[1][nt]);
    }
  }
  #pragma unroll
  for (int mt = 0; mt < 2; ++mt)
    #pragma unroll
    for (int nt = 0; nt < 4; ++nt)
      #pragma unroll
      for (int r = 0; r < 4; ++r) {
        int row = row0 + mt * 16 + q * 4 + r;
        int col = nc0 + nt * 16 + c;
        float val = fmaxf(acc[mt][nt][r] + bm1[col], 0.f);
        nh1[(size_t)row * 1024 + col] = f2bf(val);
      }
}

// K5: h = relu(nh1 @ W_m2 + b_m2), M=4096 K=1024 N=128
// grid 256 x 128 thr (2 waves: 16 rows x 64 cols each)
__global__ __launch_bounds__(128) void k5_mlp2(
    const unsigned short* __restrict__ nh1, const unsigned short* __restrict__ Wt,
    const float* __restrict__ bm2, float* __restrict__ hout) {
  int bid = blockIdx.x;
  int tid = threadIdx.x, wid = tid >> 6, lane = tid & 63;
  int row0 = bid * 16;
  int nc0 = wid * 64;
  int c = lane & 15, q = lane >> 4;
  const unsigned short* ap = nh1 + (size_t)(row0 + c) * 1024;
  const unsigned short* bb = Wt + (size_t)(nc0 + c) * 1024;
  f32x4 acc[4];
  #pragma unroll
  for (int b = 0; b < 4; ++b) acc[b] = (f32x4){0.f, 0.f, 0.f, 0.f};
  for (int ks = 0; ks < 32; ++ks) {
    int k0 = ks * 32 + q * 8;
    bf16x8 a = *(const bf16x8*)(ap + k0);
    #pragma unroll
    for (int nt = 0; nt < 4; ++nt) {
      bf16x8 bf = *(const bf16x8*)(bb + (size_t)nt * 16 * 1024 + k0);
      acc[nt] = MFMA16(a, bf, acc[nt]);
    }
  }
  #pragma unroll
  for (int nt = 0; nt < 4; ++nt)
    #pragma unroll
    for (int r = 0; r < 4; ++r) {
      int row = row0 + q * 4 + r;
      int col = nc0 + nt * 16 + c;
      hout[(size_t)row * 128 + col] = fmaxf(acc[nt][r] + bm2[col], 0.f);
    }
}

// ---------------- host ----------------

extern "C" void kernel_launch(void* const* d_in, const int* in_sizes, int n_in,
                              void* d_out, int out_size, void* d_ws, size_t ws_size,
                              hipStream_t stream) {
  const float* h0   = (const float*)d_in[0];
  const float* c0   = (const float*)d_in[1];
  const float* ofp  = (const float*)d_in[2];
  const float* ofr  = (const float*)d_in[3];
  const float* Wemb = (const float*)d_in[4];
  const float* bemb = (const float*)d_in[5];
  const float* Wih  = (const float*)d_in[6];
  const float* Whh  = (const float*)d_in[7];
  const float* bih  = (const float*)d_in[8];
  const float* bhh  = (const float*)d_in[9];
  const float* Wpos = (const float*)d_in[10];
  const float* bpos = (const float*)d_in[11];
  const float* Wpe  = (const float*)d_in[12];
  const float* bpe  = (const float*)d_in[13];
  const float* Wp1  = (const float*)d_in[14];
  const float* bp1  = (const float*)d_in[15];
  const float* Wp2  = (const float*)d_in[16];
  const float* bp2  = (const float*)d_in[17];
  const float* Wm1  = (const float*)d_in[18];
  const float* bm1  = (const float*)d_in[19];
  const float* Wm2  = (const float*)d_in[20];
  const float* bm2  = (const float*)d_in[21];

  char* ws = (char*)d_ws;
  size_t off = 0;
  auto alloc = [&](size_t bytes) {
    char* p = ws + off;
    off += (bytes + 255) & ~(size_t)255;
    return p;
  };
  float* h    = (float*)alloc((size_t)NB * HD * 4);
  float* cst  = (float*)alloc((size_t)NB * HD * 4);
  float* xbuf = (float*)alloc((size_t)NB * ED * 4);
  float* pos  = (float*)alloc((size_t)NB * 2 * 4);
  _Float16* u16 = (_Float16*)alloc((size_t)NB * 512 * 2);
  _Float16* v16 = (_Float16*)alloc((size_t)NB * 512 * 2);
  unsigned short* mi   = (unsigned short*)alloc((size_t)NB * 1152 * 2);
  unsigned short* nh1  = (unsigned short*)alloc((size_t)NB * 1024 * 2);
  float* WihT = (float*)alloc(64 * 512 * 4);
  float* WhhT = (float*)alloc(128 * 512 * 4);
  float* Wpp  = (float*)alloc(512 * 2 * 4);
  float* cvec = (float*)alloc(512 * 4);
  _Float16* Bt2 = (_Float16*)alloc((size_t)1024 * 512 * 2);
  unsigned short* Wm1t = (unsigned short*)alloc((size_t)1024 * 1152 * 2);
  unsigned short* Wm2t = (unsigned short*)alloc((size_t)128 * 1024 * 2);

  float* outc = (float*)d_out;
  float* outr = outc + (size_t)TSTEPS * NB * 2;

  k_pack_lstm_w<<<256, 256, 0, stream>>>(Wih, Whh, WihT, WhhT);
  k_pack_wpp<<<2, 256, 0, stream>>>(Wpe, bpe, Wp1, bp1, Wpp, cvec);
  k_transpose_f16<<<dim3(1024 / 32, 512 / 32), 256, 0, stream>>>(Wp2, Bt2, 512, 1024);
  k_transpose_bf<<<dim3(1024 / 32, 1152 / 32), 256, 0, stream>>>(Wm1, Wm1t, 1152, 1024);
  k_transpose_bf<<<dim3(128 / 32, 1024 / 32), 256, 0, stream>>>(Wm2, Wm2t, 1024, 128);
  k_x0<<<NB * ED / 256, 256, 0, stream>>>(ofr, Wemb, bemb, xbuf);

  for (int t = 0; t < TSTEPS; ++t) {
    const float* hin = (t == 0) ? h0 : h;
    const float* cin = (t == 0) ? c0 : cst;
    const float* lp  = (t == 0) ? ofp : pos;
    k12_lstm_uv<<<NB / 8, 256, 0, stream>>>(xbuf, hin, cin, WihT, WhhT, bih, bhh,
                                            Wpos, bpos, Wemb, bemb, lp, Wp1, Wpp, cvec,
                                            cst, mi, pos, xbuf,
                                            outc + (size_t)t * NB * 2,
                                            outr + (size_t)t * NB * 2, u16, v16);
    k3_pool<<<dim3(128, 8, 4), 256, 0, stream>>>(u16, v16, Bt2, bp2, mi);
    k4_mlp1<<<256, 512, 0, stream>>>(mi, Wm1t, bm1, nh1);
    k5_mlp2<<<256, 128, 0, stream>>>(nh1, Wm2t, bm2, h);
  }
}

// Round 6
// 2722.567 us; speedup vs baseline: 1.0987x; 1.0987x over previous
//
#include <hip/hip_runtime.h>

// ---- problem dims ----
#define NB 4096    // total peds (B)
#define HD 128     // H
#define ED 64      // E
#define NF 128     // frames
#define NP 32      // peds/frame
#define TSTEPS 12

typedef __attribute__((ext_vector_type(8))) short short8;
typedef __attribute__((ext_vector_type(8))) __bf16 bf16x8;
typedef __attribute__((ext_vector_type(8))) _Float16 f16x8;
typedef __attribute__((ext_vector_type(4))) float f32x4;

#define MFMA16(a, b, c) __builtin_amdgcn_mfma_f32_16x16x32_bf16((a), (b), (c), 0, 0, 0)
#define MFMAH(a, b, c)  __builtin_amdgcn_mfma_f32_16x16x32_f16((a), (b), (c), 0, 0, 0)

__device__ __forceinline__ unsigned short f2bf(float f) {
  unsigned int x = __float_as_uint(f);
  x += 0x7fffu + ((x >> 16) & 1u);
  return (unsigned short)(x >> 16);
}

__device__ __forceinline__ float sigm(float x) { return 1.0f / (1.0f + expf(-x)); }

__device__ __forceinline__ f16x8 relu8(f16x8 x) {
  return __builtin_elementwise_max(x, (f16x8)(_Float16)0);
}

// ---------------- pre-pass packs ----------------

__global__ __launch_bounds__(256) void k_transpose_bf(const float* __restrict__ W,
                                                      unsigned short* __restrict__ Wt,
                                                      int K, int N) {
  __shared__ float t[32][33];
  int nb = blockIdx.x * 32, kb = blockIdx.y * 32;
  int tx = threadIdx.x & 31, ty = threadIdx.x >> 5;
  #pragma unroll
  for (int r = 0; r < 32; r += 8)
    t[ty + r][tx] = W[(size_t)(kb + ty + r) * N + nb + tx];
  __syncthreads();
  #pragma unroll
  for (int r = 0; r < 32; r += 8)
    Wt[(size_t)(nb + ty + r) * K + kb + tx] = f2bf(t[tx][ty + r]);
}

// Pack Wp2 (K=512 x N=1024, fp32) into MFMA-fragment-major f16:
// Bf unit index U = (ks*64 + cb)*64 + lane ; unit = 8 f16 =
// Wp2[k = ks*32 + (lane>>4)*8 + e][col = cb*16 + (lane&15)]
__global__ __launch_bounds__(256) void k_pack_bfrag(const float* __restrict__ Wp2,
                                                    _Float16* __restrict__ Bf) {
  int U = blockIdx.x * 256 + threadIdx.x;  // 65536 units
  int l = U & 63, cb = (U >> 6) & 63, ks = U >> 12;
  int col = cb * 16 + (l & 15);
  int k0 = ks * 32 + (l >> 4) * 8;
  f16x8 r;
  #pragma unroll
  for (int e = 0; e < 8; ++e) r[e] = (_Float16)Wp2[(size_t)(k0 + e) * 1024 + col];
  *(f16x8*)(Bf + (size_t)U * 8) = r;
}

__global__ __launch_bounds__(256) void k_pack_lstm_w(const float* __restrict__ Wih,
                                                     const float* __restrict__ Whh,
                                                     float* __restrict__ WihT,
                                                     float* __restrict__ WhhT) {
  int idx = blockIdx.x * 256 + threadIdx.x;
  if (idx < 64 * 512) { int k = idx >> 9, n = idx & 511; WihT[idx] = Wih[n * 64 + k]; }
  if (idx < 128 * 512) { int k = idx >> 9, n = idx & 511; WhhT[idx] = Whh[n * 128 + k]; }
}

__global__ __launch_bounds__(256) void k_pack_wpp(const float* __restrict__ Wpe,
                                                  const float* __restrict__ bpe,
                                                  const float* __restrict__ Wp1,
                                                  const float* __restrict__ bp1,
                                                  float* __restrict__ Wpp,
                                                  float* __restrict__ cvec) {
  int n = blockIdx.x * 256 + threadIdx.x;
  if (n >= 512) return;
  float s0 = 0.f, s1 = 0.f, sc = 0.f;
  for (int k = 0; k < 64; ++k) {
    float w = Wp1[k * 512 + n];
    s0 += Wpe[k] * w;
    s1 += Wpe[64 + k] * w;
    sc += bpe[k] * w;
  }
  Wpp[n * 2] = s0; Wpp[n * 2 + 1] = s1; cvec[n] = sc + bp1[n];
}

__global__ __launch_bounds__(256) void k_x0(const float* __restrict__ ofr,
                                            const float* __restrict__ Wemb,
                                            const float* __restrict__ bemb,
                                            float* __restrict__ x) {
  int idx = blockIdx.x * 256 + threadIdx.x;
  if (idx >= NB * ED) return;
  int row = idx >> 6, e = idx & 63;
  x[idx] = bemb[e] + ofr[row * 2] * Wemb[e] + ofr[row * 2 + 1] * Wemb[64 + e];
}

// ---------------- per-step kernels ----------------

// K12: fused LSTM cell + pos + x_new + u/v build. 8 rows/block, 256 thr.
__global__ __launch_bounds__(256) void k12_lstm_uv(
    const float* __restrict__ x, const float* __restrict__ hin, const float* __restrict__ cin,
    const float* __restrict__ WihT, const float* __restrict__ WhhT,
    const float* __restrict__ bih, const float* __restrict__ bhh,
    const float* __restrict__ Wpos, const float* __restrict__ bpos,
    const float* __restrict__ Wemb, const float* __restrict__ bemb,
    const float* __restrict__ lastpos,
    const float* __restrict__ Wp1, const float* __restrict__ Wpp,
    const float* __restrict__ cvec,
    float* __restrict__ cout, unsigned short* __restrict__ mi,
    float* __restrict__ posout, float* __restrict__ xout,
    float* __restrict__ outc, float* __restrict__ outr,
    _Float16* __restrict__ u16, _Float16* __restrict__ v16) {
  __shared__ float xh[8][192];
  __shared__ float hnl[8][128];
  __shared__ float rp[8][2];
  __shared__ float cp[8][2];
  int tid = threadIdx.x;
  int r0 = blockIdx.x * 8;
  for (int idx = tid; idx < 8 * 192; idx += 256) {
    int r = idx / 192, k = idx % 192;
    xh[r][k] = (k < 64) ? x[(r0 + r) * 64 + k] : hin[(r0 + r) * 128 + (k - 64)];
  }
  __syncthreads();
  int j = tid & 127, rg = tid >> 7;
  float acc0[4], acc1[4], acc2[4], acc3[4];
  {
    float b0 = bih[j] + bhh[j];
    float b1 = bih[128 + j] + bhh[128 + j];
    float b2 = bih[256 + j] + bhh[256 + j];
    float b3 = bih[384 + j] + bhh[384 + j];
    #pragma unroll
    for (int r = 0; r < 4; ++r) { acc0[r] = b0; acc1[r] = b1; acc2[r] = b2; acc3[r] = b3; }
  }
  for (int k = 0; k < 64; ++k) {
    float w0 = WihT[k * 512 + j], w1 = WihT[k * 512 + 128 + j],
          w2 = WihT[k * 512 + 256 + j], w3 = WihT[k * 512 + 384 + j];
    #pragma unroll
    for (int r = 0; r < 4; ++r) {
      float xv = xh[rg * 4 + r][k];
      acc0[r] += w0 * xv; acc1[r] += w1 * xv; acc2[r] += w2 * xv; acc3[r] += w3 * xv;
    }
  }
  for (int k = 0; k < 128; ++k) {
    float w0 = WhhT[k * 512 + j], w1 = WhhT[k * 512 + 128 + j],
          w2 = WhhT[k * 512 + 256 + j], w3 = WhhT[k * 512 + 384 + j];
    #pragma unroll
    for (int r = 0; r < 4; ++r) {
      float hv = xh[rg * 4 + r][64 + k];
      acc0[r] += w0 * hv; acc1[r] += w1 * hv; acc2[r] += w2 * hv; acc3[r] += w3 * hv;
    }
  }
  #pragma unroll
  for (int r = 0; r < 4; ++r) {
    int row = r0 + rg * 4 + r;
    float ig = sigm(acc0[r]), fg = sigm(acc1[r]), gg = tanhf(acc2[r]), og = sigm(acc3[r]);
    float cn = fg * cin[row * 128 + j] + ig * gg;
    float hv = og * tanhf(cn);
    cout[row * 128 + j] = cn;
    mi[(size_t)row * 1152 + j] = f2bf(hv);
    hnl[rg * 4 + r][j] = hv;
  }
  __syncthreads();
  // parallel W_pos dot: 16 lanes per (row, dim)
  {
    int r = tid >> 5;
    int d = (tid >> 4) & 1;
    int l = tid & 15;
    float s = 0.f;
    #pragma unroll
    for (int k = l; k < 128; k += 16) s += hnl[r][k] * Wpos[k * 2 + d];
    s += __shfl_xor(s, 1);
    s += __shfl_xor(s, 2);
    s += __shfl_xor(s, 4);
    s += __shfl_xor(s, 8);
    if (l == 0) {
      int row = r0 + r;
      float rel = s + bpos[d];
      float cur = rel + lastpos[row * 2 + d];
      rp[r][d] = rel;
      cp[r][d] = cur;
      posout[row * 2 + d] = cur;
      outc[row * 2 + d] = cur;
      outr[row * 2 + d] = rel;
    }
  }
  __syncthreads();
  for (int idx = tid; idx < 8 * 64; idx += 256) {
    int r = idx >> 6, e = idx & 63;
    xout[(r0 + r) * 64 + e] = bemb[e] + rp[r][0] * Wemb[e] + rp[r][1] * Wemb[64 + e];
  }
  // ---- k2 part: u/v build (f16 out) ----
  int n = tid, n2 = tid + 256;
  float aA[8], aB[8];
  #pragma unroll
  for (int r = 0; r < 8; ++r) { aA[r] = 0.f; aB[r] = 0.f; }
  for (int k = 0; k < 128; ++k) {
    float wA = Wp1[(64 + k) * 512 + n], wB = Wp1[(64 + k) * 512 + n2];
    #pragma unroll
    for (int r = 0; r < 8; ++r) { aA[r] += wA * hnl[r][k]; aB[r] += wB * hnl[r][k]; }
  }
  float wp0A = Wpp[n * 2], wp1A = Wpp[n * 2 + 1], cA = cvec[n];
  float wp0B = Wpp[n2 * 2], wp1B = Wpp[n2 * 2 + 1], cB = cvec[n2];
  #pragma unroll
  for (int r = 0; r < 8; ++r) {
    int row = r0 + r;
    float t0 = cp[r][0] * wp0A + cp[r][1] * wp1A;
    v16[(size_t)row * 512 + n] = (_Float16)t0;
    u16[(size_t)row * 512 + n] = (_Float16)(t0 + aA[r] + cA);
    float t1 = cp[r][0] * wp0B + cp[r][1] * wp1B;
    v16[(size_t)row * 512 + n2] = (_Float16)t1;
    u16[(size_t)row * 512 + n2] = (_Float16)(t1 + aB[r] + cB);
  }
}

// K3 v6: pool_h[f,i,n] = relu(max_j ( relu(u_j - v_i) @ Wp2 )[n] + bp2[n])
// grid (128 f, 8 ig, 4 ng); 256 thr = 4 waves = 2 ip x 2 nh.
// B: fragment-major global -> register double-buffer (1KB coalesced loads, L2-hot).
// u: whole frame in LDS at prologue, XOR-swizzled (byte ^= (row&7)<<4).
// v: 4 rows in LDS (broadcast reads). ZERO barriers / LDS writes in K-loop.
__global__ __launch_bounds__(256, 2) void k3_pool(
    const _Float16* __restrict__ u16, const _Float16* __restrict__ v16,
    const _Float16* __restrict__ Bf, const float* __restrict__ bp2,
    unsigned short* __restrict__ mi) {
  __shared__ _Float16 u_lds[32 * 512];   // 32 KB
  __shared__ _Float16 v_lds[4 * 512];    //  4 KB
  int f = blockIdx.x, ig = blockIdx.y, ng = blockIdx.z;
  int tid = threadIdx.x, wid = tid >> 6, lane = tid & 63;
  int c = lane & 15, q = lane >> 4;
  int ip = wid >> 1, nh = wid & 1;

  const f16x8* Bfu = (const f16x8*)Bf;
  int cb0 = ng * 16 + nh * 8;

  // issue first B-fragment loads (overlap with staging + barrier)
  f16x8 B0[8], B1[8];
  #pragma unroll
  for (int nt = 0; nt < 8; ++nt)
    B0[nt] = Bfu[(size_t)((cb0 + nt) * 64 + lane)];

  // stage u (swizzled rows) and v
  #pragma unroll
  for (int t = 0; t < 8; ++t) {
    int unit = tid + t * 256;
    int row = unit >> 6, seg = unit & 63;
    f16x8 val = *(const f16x8*)(u16 + (size_t)(f * 32 + row) * 512 + seg * 8);
    int byte = (row << 10) + (seg << 4);
    byte ^= (row & 7) << 4;
    *(f16x8*)((char*)u_lds + byte) = val;
  }
  {
    int row = tid >> 6, seg = tid & 63;
    *(f16x8*)(v_lds + (row << 9) + seg * 8) =
        *(const f16x8*)(v16 + (size_t)(f * 32 + ig * 4 + row) * 512 + seg * 8);
  }
  __syncthreads();

  f32x4 acc[2][2][8];  // [ii][jg][nt]
  #pragma unroll
  for (int a = 0; a < 2; ++a)
    #pragma unroll
    for (int b = 0; b < 2; ++b)
      #pragma unroll
      for (int n = 0; n < 8; ++n) acc[a][b][n] = (f32x4){0.f, 0.f, 0.f, 0.f};

  int ub0 = (c << 10) + (q << 4);     // u row c base byte (pre-swizzle)
  int usw = (c & 7) << 4;             // same for row c+16
  const _Float16* vp0 = v_lds + ((ip * 2 + 0) << 9) + q * 8;
  const _Float16* vp1 = vp0 + 512;

  #pragma unroll
  for (int ks = 0; ks < 16; ++ks) {
    if (ks < 15) {
      #pragma unroll
      for (int nt = 0; nt < 8; ++nt)
        B1[nt] = Bfu[(size_t)(((ks + 1) * 64 + cb0 + nt) * 64 + lane)];
    }
    int kb = ks << 6;  // k-step byte offset within a row
    f16x8 uf0 = *(const f16x8*)((const char*)u_lds + ((ub0 + kb) ^ usw));
    f16x8 uf1 = *(const f16x8*)((const char*)u_lds + ((ub0 + 16384 + kb) ^ usw));
    f16x8 vv0 = *(const f16x8*)(vp0 + ks * 32);
    f16x8 vv1 = *(const f16x8*)(vp1 + ks * 32);
    f16x8 a00 = relu8(uf0 - vv0), a01 = relu8(uf1 - vv0);
    f16x8 a10 = relu8(uf0 - vv1), a11 = relu8(uf1 - vv1);
    __builtin_amdgcn_s_setprio(1);
    #pragma unroll
    for (int nt = 0; nt < 8; ++nt) {
      f16x8 bf = B0[nt];
      acc[0][0][nt] = MFMAH(a00, bf, acc[0][0][nt]);
      acc[0][1][nt] = MFMAH(a01, bf, acc[0][1][nt]);
      acc[1][0][nt] = MFMAH(a10, bf, acc[1][0][nt]);
      acc[1][1][nt] = MFMAH(a11, bf, acc[1][1][nt]);
    }
    __builtin_amdgcn_s_setprio(0);
    #pragma unroll
    for (int nt = 0; nt < 8; ++nt) B0[nt] = B1[nt];
  }

  // epilogue: max over j, relu(+bias), write bf16
  int colbase = ng * 256 + nh * 128;
  #pragma unroll
  for (int ii = 0; ii < 2; ++ii) {
    int rowg = f * 32 + ig * 4 + ip * 2 + ii;
    #pragma unroll
    for (int nt = 0; nt < 8; ++nt) {
      f32x4 x0 = acc[ii][0][nt], x1 = acc[ii][1][nt];
      float m = fmaxf(fmaxf(fmaxf(x0[0], x0[1]), fmaxf(x0[2], x0[3])),
                      fmaxf(fmaxf(x1[0], x1[1]), fmaxf(x1[2], x1[3])));
      m = fmaxf(m, __shfl_xor(m, 16));
      m = fmaxf(m, __shfl_xor(m, 32));
      if (q == 0) {
        int col = colbase + nt * 16 + c;
        float val = fmaxf(m + bp2[col], 0.f);
        mi[(size_t)rowg * 1152 + 128 + col] = f2bf(val);
      }
    }
  }
}

// K4: nh1 = relu(mi @ W_m1 + b_m1), M=4096 K=1152 N=1024 (bf16 MFMA)
__global__ __launch_bounds__(512) void k4_mlp1(
    const unsigned short* __restrict__ mi, const unsigned short* __restrict__ Wt,
    const float* __restrict__ bm1, unsigned short* __restrict__ nh1) {
  int bid = blockIdx.x;
  int mb = bid & 63, nb = bid >> 6;
  int tid = threadIdx.x, wid = tid >> 6, lane = tid & 63;
  int row0 = mb * 64 + (wid >> 2) * 32;
  int nc0 = nb * 256 + (wid & 3) * 64;
  int c = lane & 15, q = lane >> 4;
  const unsigned short* a0p = mi + (size_t)(row0 + c) * 1152;
  const unsigned short* a1p = a0p + 16 * 1152;
  const unsigned short* bb = Wt + (size_t)(nc0 + c) * 1152;
  f32x4 acc[2][4];
  #pragma unroll
  for (int a = 0; a < 2; ++a)
    #pragma unroll
    for (int b = 0; b < 4; ++b) acc[a][b] = (f32x4){0.f, 0.f, 0.f, 0.f};
  for (int ks = 0; ks < 36; ++ks) {
    int k0 = ks * 32 + q * 8;
    bf16x8 a0 = *(const bf16x8*)(a0p + k0);
    bf16x8 a1 = *(const bf16x8*)(a1p + k0);
    #pragma unroll
    for (int nt = 0; nt < 4; ++nt) {
      bf16x8 bf = *(const bf16x8*)(bb + (size_t)nt * 16 * 1152 + k0);
      acc[0][nt] = MFMA16(a0, bf, acc[0][nt]);
      acc[1][nt] = MFMA16(a1, bf, acc[1][nt]);
    }
  }
  #pragma unroll
  for (int mt = 0; mt < 2; ++mt)
    #pragma unroll
    for (int nt = 0; nt < 4; ++nt)
      #pragma unroll
      for (int r = 0; r < 4; ++r) {
        int row = row0 + mt * 16 + q * 4 + r;
        int col = nc0 + nt * 16 + c;
        float val = fmaxf(acc[mt][nt][r] + bm1[col], 0.f);
        nh1[(size_t)row * 1024 + col] = f2bf(val);
      }
}

// K5: h = relu(nh1 @ W_m2 + b_m2), M=4096 K=1024 N=128
__global__ __launch_bounds__(128) void k5_mlp2(
    const unsigned short* __restrict__ nh1, const unsigned short* __restrict__ Wt,
    const float* __restrict__ bm2, float* __restrict__ hout) {
  int bid = blockIdx.x;
  int tid = threadIdx.x, wid = tid >> 6, lane = tid & 63;
  int row0 = bid * 16;
  int nc0 = wid * 64;
  int c = lane & 15, q = lane >> 4;
  const unsigned short* ap = nh1 + (size_t)(row0 + c) * 1024;
  const unsigned short* bb = Wt + (size_t)(nc0 + c) * 1024;
  f32x4 acc[4];
  #pragma unroll
  for (int b = 0; b < 4; ++b) acc[b] = (f32x4){0.f, 0.f, 0.f, 0.f};
  for (int ks = 0; ks < 32; ++ks) {
    int k0 = ks * 32 + q * 8;
    bf16x8 a = *(const bf16x8*)(ap + k0);
    #pragma unroll
    for (int nt = 0; nt < 4; ++nt) {
      bf16x8 bf = *(const bf16x8*)(bb + (size_t)nt * 16 * 1024 + k0);
      acc[nt] = MFMA16(a, bf, acc[nt]);
    }
  }
  #pragma unroll
  for (int nt = 0; nt < 4; ++nt)
    #pragma unroll
    for (int r = 0; r < 4; ++r) {
      int row = row0 + q * 4 + r;
      int col = nc0 + nt * 16 + c;
      hout[(size_t)row * 128 + col] = fmaxf(acc[nt][r] + bm2[col], 0.f);
    }
}

// ---------------- host ----------------

extern "C" void kernel_launch(void* const* d_in, const int* in_sizes, int n_in,
                              void* d_out, int out_size, void* d_ws, size_t ws_size,
                              hipStream_t stream) {
  const float* h0   = (const float*)d_in[0];
  const float* c0   = (const float*)d_in[1];
  const float* ofp  = (const float*)d_in[2];
  const float* ofr  = (const float*)d_in[3];
  const float* Wemb = (const float*)d_in[4];
  const float* bemb = (const float*)d_in[5];
  const float* Wih  = (const float*)d_in[6];
  const float* Whh  = (const float*)d_in[7];
  const float* bih  = (const float*)d_in[8];
  const float* bhh  = (const float*)d_in[9];
  const float* Wpos = (const float*)d_in[10];
  const float* bpos = (const float*)d_in[11];
  const float* Wpe  = (const float*)d_in[12];
  const float* bpe  = (const float*)d_in[13];
  const float* Wp1  = (const float*)d_in[14];
  const float* bp1  = (const float*)d_in[15];
  const float* Wp2  = (const float*)d_in[16];
  const float* bp2  = (const float*)d_in[17];
  const float* Wm1  = (const float*)d_in[18];
  const float* bm1  = (const float*)d_in[19];
  const float* Wm2  = (const float*)d_in[20];
  const float* bm2  = (const float*)d_in[21];

  char* ws = (char*)d_ws;
  size_t off = 0;
  auto alloc = [&](size_t bytes) {
    char* p = ws + off;
    off += (bytes + 255) & ~(size_t)255;
    return p;
  };
  float* h    = (float*)alloc((size_t)NB * HD * 4);
  float* cst  = (float*)alloc((size_t)NB * HD * 4);
  float* xbuf = (float*)alloc((size_t)NB * ED * 4);
  float* pos  = (float*)alloc((size_t)NB * 2 * 4);
  _Float16* u16 = (_Float16*)alloc((size_t)NB * 512 * 2);
  _Float16* v16 = (_Float16*)alloc((size_t)NB * 512 * 2);
  unsigned short* mi   = (unsigned short*)alloc((size_t)NB * 1152 * 2);
  unsigned short* nh1  = (unsigned short*)alloc((size_t)NB * 1024 * 2);
  float* WihT = (float*)alloc(64 * 512 * 4);
  float* WhhT = (float*)alloc(128 * 512 * 4);
  float* Wpp  = (float*)alloc(512 * 2 * 4);
  float* cvec = (float*)alloc(512 * 4);
  _Float16* Bf  = (_Float16*)alloc((size_t)1024 * 512 * 2);
  unsigned short* Wm1t = (unsigned short*)alloc((size_t)1024 * 1152 * 2);
  unsigned short* Wm2t = (unsigned short*)alloc((size_t)128 * 1024 * 2);

  float* outc = (float*)d_out;
  float* outr = outc + (size_t)TSTEPS * NB * 2;

  k_pack_lstm_w<<<256, 256, 0, stream>>>(Wih, Whh, WihT, WhhT);
  k_pack_wpp<<<2, 256, 0, stream>>>(Wpe, bpe, Wp1, bp1, Wpp, cvec);
  k_pack_bfrag<<<256, 256, 0, stream>>>(Wp2, Bf);
  k_transpose_bf<<<dim3(1024 / 32, 1152 / 32), 256, 0, stream>>>(Wm1, Wm1t, 1152, 1024);
  k_transpose_bf<<<dim3(128 / 32, 1024 / 32), 256, 0, stream>>>(Wm2, Wm2t, 1024, 128);
  k_x0<<<NB * ED / 256, 256, 0, stream>>>(ofr, Wemb, bemb, xbuf);

  for (int t = 0; t < TSTEPS; ++t) {
    const float* hin = (t == 0) ? h0 : h;
    const float* cin = (t == 0) ? c0 : cst;
    const float* lp  = (t == 0) ? ofp : pos;
    k12_lstm_uv<<<NB / 8, 256, 0, stream>>>(xbuf, hin, cin, WihT, WhhT, bih, bhh,
                                            Wpos, bpos, Wemb, bemb, lp, Wp1, Wpp, cvec,
                                            cst, mi, pos, xbuf,
                                            outc + (size_t)t * NB * 2,
                                            outr + (size_t)t * NB * 2, u16, v16);
    k3_pool<<<dim3(128, 8, 4), 256, 0, stream>>>(u16, v16, Bf, bp2, mi);
    k4_mlp1<<<256, 512, 0, stream>>>(mi, Wm1t, bm1, nh1);
    k5_mlp2<<<256, 128, 0, stream>>>(nh1, Wm2t, bm2, h);
  }
}